// Round 19
// baseline (145.913 us; speedup 1.0000x reference)
//
#include <hip/hip_runtime.h>
#include <hip/hip_bf16.h>

// Problem geometry
#define E_CNT  256
#define D_IN   15
#define HDIM   128
#define BATCH  8192
#define NQUAD  128                  // 128 quads of 4x16-row chunks per expert
#define BPE    4                    // blocks per expert -> grid 1024, 4 blocks/CU
#define NL2E   -1.44269504088896341f

typedef float f32x4 __attribute__((ext_vector_type(4)));
typedef short bf16x8 __attribute__((ext_vector_type(8)));
typedef unsigned int uint4v __attribute__((ext_vector_type(4)));

#define MFMA16(a, b, c) __builtin_amdgcn_mfma_f32_16x16x32_bf16((a), (b), (c), 0, 0, 0)
#define SCHED_FENCE() __builtin_amdgcn_sched_barrier(0)

// bf16 via round-half-up on the bit pattern (values finite here).
static __device__ inline unsigned short f2bf_rnd(float f) {
    unsigned u = __builtin_bit_cast(unsigned, f);
    return (unsigned short)((u + 0x8000u) >> 16);
}

// sigmoid with pre-scaled input az = -z*log2(e): s = rcp(1 + 2^az).
static __device__ inline float sg(float az) {
    float e = __builtin_amdgcn_exp2f(az);
    return __builtin_amdgcn_rcpf(1.0f + e);
}

// pack two sigmoid outputs ([0,1]) to a bf16 pair by TRUNCATION: 1 op.
// (<=1 ulp negative bias; random-sign w2 cancels it in the L2 sum — R18-proven.
//  NOT hand-written v_cvt_pk_bf16_f32: that asm corrupted results in R2/R14.)
static __device__ inline unsigned pack2t(float lo, float hi_) {
    unsigned a = __builtin_bit_cast(unsigned, lo);
    unsigned b = __builtin_bit_cast(unsigned, hi_);
#if __has_builtin(__builtin_amdgcn_perm)
    return __builtin_amdgcn_perm(b, a, 0x07060302u);   // D = {a.b2,a.b3,b.b2,b.b3}
#else
    return (a >> 16) | (b & 0xffff0000u);
#endif
}

// v_permlane32_swap_b32: a' = {a.g0,a.g1,b.g0,b.g1}, b' = {a.g2,a.g3,b.g2,b.g3}
static __device__ inline void pl32swap(unsigned &a, unsigned &b) {
#if __has_builtin(__builtin_amdgcn_permlane32_swap)
    auto r = __builtin_amdgcn_permlane32_swap(a, b, false, false);
    a = (unsigned)r[0];
    b = (unsigned)r[1];
#else
    asm volatile("v_permlane32_swap_b32 %0, %1" : "+v"(a), "+v"(b));
#endif
}

// v_permlane16_swap_b32: a' = {a.g0,b.g0,a.g2,b.g2}, b' = {a.g1,b.g1,a.g3,b.g3}
static __device__ inline void pl16swap(unsigned &a, unsigned &b) {
#if __has_builtin(__builtin_amdgcn_permlane16_swap)
    auto r = __builtin_amdgcn_permlane16_swap(a, b, false, false);
    a = (unsigned)r[0];
    b = (unsigned)r[1];
#else
    asm volatile("v_permlane16_swap_b32 %0, %1" : "+v"(a), "+v"(b));
#endif
}

static __device__ inline f32x4 zero4() { f32x4 z = {0.f, 0.f, 0.f, 0.f}; return z; }

// Redistribute two 16x16 C-tiles (pair-packed sigmoids) into one K=32 B-frag.
// (validated on-device R8-R18: absmax 0.0078)
static __device__ inline bf16x8 mk_bfrag(unsigned X0, unsigned X1, unsigned Y0, unsigned Y1) {
    pl32swap(X0, Y0);
    pl32swap(X1, Y1);
    pl16swap(X0, Y0);
    pl16swap(X1, Y1);
    uint4v u = {X0, X1, Y0, Y1};
    return __builtin_bit_cast(bf16x8, u);
}

// x[B][15] f32 -> xbf[B][16] bf16 with slot 15 = 1.0 (b1 partner)
__global__ __launch_bounds__(256)
void prep_x_kernel(const float* __restrict__ x, unsigned short* __restrict__ xbf)
{
    int i = blockIdx.x * 256 + threadIdx.x;
    if (i >= BATCH * 16) return;
    int row = i >> 4, k = i & 15;
    float v = (k < D_IN) ? x[row * D_IN + k] : 1.0f;
    xbf[i] = f2bf_rnd(v);
}

// 16x16x32 MFMA MLP, QUAD-chunk (4x16 rows/iter), fragment-ordered LDS.
// Every weight fragment read feeds FOUR chunks' MFMAs (shared-read cost
// halves vs dual). L1 built in two half-passes (A,B then C,D) + fences to
// bound transient pressure; w1 zero-select hoisted to base+stride (no
// per-read cndmask). Ledger: ~88 arch + 24 acc ~= 112 < 128 cap at (256,4).
__global__ __launch_bounds__(256, 4)
void mlp256_kernel(const float* __restrict__ x, const unsigned short* __restrict__ xbf,
                   const float* __restrict__ W1, const float* __restrict__ b1,
                   const float* __restrict__ W2, const float* __restrict__ b2,
                   const float* __restrict__ W3, const float* __restrict__ b3,
                   float* __restrict__ dst, int use_xbf, int transposed)
{
    __shared__ __align__(16) unsigned short w2f[32 * 512];   // 32 KB
    __shared__ __align__(16) unsigned short w1f[8 * 256];    // 4 KB (lanes<32)
    __shared__ __align__(16) float          b2l[128];        // 512 B (f32, scaled)
    __shared__ __align__(16) float          w3l[128];        // 512 B (f32, natural)
    __shared__ __align__(16) unsigned short zb[8];           // shared zero line

    const int tid  = threadIdx.x;
    const int wave = tid >> 6;
    const int lane = tid & 63;
    const int l15  = lane & 15;
    const int q    = lane >> 4;

    // grid = 1024: e = bid&255, rg = bid>>8 (0..3). Blocks e,e+256,e+512,e+768
    // share bid%8 -> same XCD under round-robin dispatch (W2 in one L2).
    const int bid = blockIdx.x;
    const int e   = bid & 255;
    const int rg  = bid >> 8;

    const float* w1p = W1 + e * (D_IN * HDIM);
    const float* b1p = b1 + e * HDIM;
    const float* w2p = W2 + e * (HDIM * HDIM);
    const float* b2p = b2 + e * HDIM;
    const float* w3p = W3 + e * HDIM;
    const float  b3v = b3[e];

    // ---- stage weights, fragment-ordered (prologue only) ----
    // W2: src (h,k) -> tile (h>>4)*4 + (k>>5), lane ((k>>3)&3)*16 + (h&15), j=k&7
    for (int i = tid; i < HDIM * HDIM; i += 256) {
        int h = i & 127, k = i >> 7;
        int t = ((h >> 4) << 2) + (k >> 5);
        int ln = (((k >> 3) & 3) << 4) + (h & 15);
        w2f[t * 512 + ln * 8 + (k & 7)] = f2bf_rnd(w2p[k * HDIM + h] * NL2E);
    }
    // W1 (+b1): 8 tiles x 32 lanes x 8; k = (ln>>4)*8 + j in 0..15
    for (int i = tid; i < 8 * 256; i += 256) {
        int t = i >> 8, ln = (i >> 3) & 31, j = i & 7;
        int k = (ln >> 4) * 8 + j, h = t * 16 + (ln & 15);
        float v = (k < D_IN) ? w1p[k * HDIM + h] : b1p[h];
        w1f[i] = f2bf_rnd(v * NL2E);
    }
    // b2 (scaled) as accumulator C-init; w3 f32 natural; zero line
    if (tid < 128) b2l[tid] = b2p[tid] * NL2E;
    if (tid < 128) w3l[tid] = w3p[tid];
    if (tid < 8)   zb[tid] = 0;

    __syncthreads();   // weights staged; waves independent from here

    // per-lane bases; w1 zero-select hoisted into base+stride (no per-read cndmask)
    const bool w1s = (lane < 32);
    const unsigned short* w1S = w1s ? (w1f + lane * 8) : zb;
    const int w1stride = w1s ? 256 : 0;
    const unsigned short* w2B = w2f + lane * 8;        // + tile*512
    const float*          b2D = b2l + q * 4;           // + ot*16 (l15-independent)
    const float*          w3V = w3l + q * 4;           // + ot*16 (l15-independent)
    const int xoff = l15 * 16 + (q & 1) * 8;

    // quads: slot = rg + 4*wave (0..15); p = slot + 16*j, 8 quads per wave
    for (int p = rg + 4 * wave; p < NQUAD; p += 16) {
        const int c0 = 4 * p;

        bf16x8 H1A[4], H1B[4], H1C[4], H1D[4];

        // ---- L1 half 1: chunks A,B ----
        {
            bf16x8 XA, XB_;
            if (use_xbf) {
                XA  = *reinterpret_cast<const bf16x8*>(xbf + (size_t)(c0 + 0) * 256 + xoff);
                XB_ = *reinterpret_cast<const bf16x8*>(xbf + (size_t)(c0 + 1) * 256 + xoff);
            } else {
                const float* xa = x + (size_t)((c0 + 0) * 16 + l15) * D_IN;
                const float* xb = x + (size_t)((c0 + 1) * 16 + l15) * D_IN;
#pragma unroll
                for (int j = 0; j < 8; ++j) {
                    int k = (q & 1) * 8 + j;
                    XA[j]  = (short)f2bf_rnd((k < D_IN) ? xa[k] : 1.0f);
                    XB_[j] = (short)f2bf_rnd((k < D_IN) ? xb[k] : 1.0f);
                }
            }
#pragma unroll
            for (int kb = 0; kb < 4; ++kb) {
                bf16x8 wa0 = *reinterpret_cast<const bf16x8*>(w1S + (2 * kb) * w1stride);
                f32x4 aa = MFMA16(wa0, XA,  zero4());
                f32x4 ba = MFMA16(wa0, XB_, zero4());
                bf16x8 wa1 = *reinterpret_cast<const bf16x8*>(w1S + (2 * kb + 1) * w1stride);
                f32x4 ab = MFMA16(wa1, XA,  zero4());
                f32x4 bb = MFMA16(wa1, XB_, zero4());
                H1A[kb] = mk_bfrag(pack2t(sg(aa[0]), sg(aa[1])), pack2t(sg(aa[2]), sg(aa[3])),
                                   pack2t(sg(ab[0]), sg(ab[1])), pack2t(sg(ab[2]), sg(ab[3])));
                H1B[kb] = mk_bfrag(pack2t(sg(ba[0]), sg(ba[1])), pack2t(sg(ba[2]), sg(ba[3])),
                                   pack2t(sg(bb[0]), sg(bb[1])), pack2t(sg(bb[2]), sg(bb[3])));
            }
        }
        SCHED_FENCE();

        // ---- L1 half 2: chunks C,D ----
        {
            bf16x8 XC, XD;
            if (use_xbf) {
                XC = *reinterpret_cast<const bf16x8*>(xbf + (size_t)(c0 + 2) * 256 + xoff);
                XD = *reinterpret_cast<const bf16x8*>(xbf + (size_t)(c0 + 3) * 256 + xoff);
            } else {
                const float* xc = x + (size_t)((c0 + 2) * 16 + l15) * D_IN;
                const float* xd = x + (size_t)((c0 + 3) * 16 + l15) * D_IN;
#pragma unroll
                for (int j = 0; j < 8; ++j) {
                    int k = (q & 1) * 8 + j;
                    XC[j] = (short)f2bf_rnd((k < D_IN) ? xc[k] : 1.0f);
                    XD[j] = (short)f2bf_rnd((k < D_IN) ? xd[k] : 1.0f);
                }
            }
#pragma unroll
            for (int kb = 0; kb < 4; ++kb) {
                bf16x8 wa0 = *reinterpret_cast<const bf16x8*>(w1S + (2 * kb) * w1stride);
                f32x4 ca = MFMA16(wa0, XC, zero4());
                f32x4 da = MFMA16(wa0, XD, zero4());
                bf16x8 wa1 = *reinterpret_cast<const bf16x8*>(w1S + (2 * kb + 1) * w1stride);
                f32x4 cb = MFMA16(wa1, XC, zero4());
                f32x4 db = MFMA16(wa1, XD, zero4());
                H1C[kb] = mk_bfrag(pack2t(sg(ca[0]), sg(ca[1])), pack2t(sg(ca[2]), sg(ca[3])),
                                   pack2t(sg(cb[0]), sg(cb[1])), pack2t(sg(cb[2]), sg(cb[3])));
                H1D[kb] = mk_bfrag(pack2t(sg(da[0]), sg(da[1])), pack2t(sg(da[2]), sg(da[3])),
                                   pack2t(sg(db[0]), sg(db[1])), pack2t(sg(db[2]), sg(db[3])));
            }
        }
        SCHED_FENCE();

        // ---- layer 2 (MFMA, b2 as C-init, weight read shared x4) + L3 VALU dot ----
        float oA = 0.0f, oB = 0.0f, oC = 0.0f, oD = 0.0f;
#pragma unroll
        for (int ot = 0; ot < 8; ++ot) {
            f32x4 binit = *reinterpret_cast<const f32x4*>(b2D + ot * 16);
            f32x4 cA2 = binit, cB2 = binit, cC2 = binit, cD2 = binit;
#pragma unroll
            for (int kb = 0; kb < 4; ++kb) {
                bf16x8 wa = *reinterpret_cast<const bf16x8*>(w2B + (ot * 4 + kb) * 512);
                cA2 = MFMA16(wa, H1A[kb], cA2);
                cB2 = MFMA16(wa, H1B[kb], cB2);
                cC2 = MFMA16(wa, H1C[kb], cC2);
                cD2 = MFMA16(wa, H1D[kb], cD2);
            }
            // lane (q,l15) reg r holds pre-act of h = ot*16 + q*4 + r, col l15
            f32x4 w3v = *reinterpret_cast<const f32x4*>(w3V + ot * 16);
#pragma unroll
            for (int r = 0; r < 4; ++r) {
                oA += sg(cA2[r]) * w3v[r];
                oB += sg(cB2[r]) * w3v[r];
                oC += sg(cC2[r]) * w3v[r];
                oD += sg(cD2[r]) * w3v[r];
            }
        }

        // cross-q reduce (cols split over 4 quarter-groups)
        oA += __shfl_xor(oA, 16);  oA += __shfl_xor(oA, 32);
        oB += __shfl_xor(oB, 16);  oB += __shfl_xor(oB, 32);
        oC += __shfl_xor(oC, 16);  oC += __shfl_xor(oC, 32);
        oD += __shfl_xor(oD, 16);  oD += __shfl_xor(oD, 32);

        if (q == 0) {   // col = l15
            const int bb0 = (c0 + 0) * 16 + l15;
            const int bb1 = (c0 + 1) * 16 + l15;
            const int bb2 = (c0 + 2) * 16 + l15;
            const int bb3 = (c0 + 3) * 16 + l15;
            if (transposed) {
                dst[(size_t)e * BATCH + bb0] = oA + b3v;
                dst[(size_t)e * BATCH + bb1] = oB + b3v;
                dst[(size_t)e * BATCH + bb2] = oC + b3v;
                dst[(size_t)e * BATCH + bb3] = oD + b3v;
            } else {
                dst[(size_t)bb0 * E_CNT + e] = oA + b3v;
                dst[(size_t)bb1 * E_CNT + e] = oB + b3v;
                dst[(size_t)bb2 * E_CNT + e] = oC + b3v;
                dst[(size_t)bb3 * E_CNT + e] = oD + b3v;
            }
        }
    }
}

// wsT[e][b] (256 x 8192) -> out[b][e] (8192 x 256), 64x64 LDS tiles
__global__ __launch_bounds__(256)
void transpose_out_kernel(const float* __restrict__ wsT, float* __restrict__ out)
{
    __shared__ float tile[64][65];
    const int tx = threadIdx.x & 63;
    const int ty = threadIdx.x >> 6;
    const int b0 = blockIdx.x * 64;
    const int e0 = blockIdx.y * 64;
#pragma unroll
    for (int r = ty; r < 64; r += 4)
        tile[r][tx] = wsT[(size_t)(e0 + r) * BATCH + b0 + tx];
    __syncthreads();
#pragma unroll
    for (int r = ty; r < 64; r += 4)
        out[(size_t)(b0 + r) * E_CNT + e0 + tx] = tile[tx][r];
}

extern "C" void kernel_launch(void* const* d_in, const int* in_sizes, int n_in,
                              void* d_out, int out_size, void* d_ws, size_t ws_size,
                              hipStream_t stream) {
    const float* x  = (const float*)d_in[0];
    const float* W1 = (const float*)d_in[1];
    const float* b1 = (const float*)d_in[2];
    const float* W2 = (const float*)d_in[3];
    const float* b2 = (const float*)d_in[4];
    const float* W3 = (const float*)d_in[5];
    const float* b3 = (const float*)d_in[6];
    float* out = (float*)d_out;

    const size_t XBF_BYTES = (size_t)BATCH * 16 * sizeof(unsigned short);  // 256 KB
    const size_t WST_BYTES = (size_t)E_CNT * BATCH * sizeof(float);        // 8 MB

    const bool have_xbf = ws_size >= XBF_BYTES + WST_BYTES;
    const bool have_wst = ws_size >= WST_BYTES;

    unsigned short* xbf = (unsigned short*)d_ws;
    float* wsT = have_xbf ? (float*)((char*)d_ws + XBF_BYTES) : (float*)d_ws;

    if (have_xbf)
        prep_x_kernel<<<dim3((BATCH * 16 + 255) / 256), dim3(256), 0, stream>>>(x, xbf);

    if (have_wst) {
        mlp256_kernel<<<dim3(E_CNT * BPE), dim3(256), 0, stream>>>(
            x, xbf, W1, b1, W2, b2, W3, b3, wsT, have_xbf ? 1 : 0, 1);
        transpose_out_kernel<<<dim3(BATCH / 64, E_CNT / 64), dim3(256), 0, stream>>>(
            wsT, out);
    } else {
        mlp256_kernel<<<dim3(E_CNT * BPE), dim3(256), 0, stream>>>(
            x, xbf, W1, b1, W2, b2, W3, b3, out, 0, 0);
    }
}

// Round 20
// 142.264 us; speedup vs baseline: 1.0257x; 1.0257x over previous
//
#include <hip/hip_runtime.h>
#include <hip/hip_bf16.h>

// Problem geometry
#define E_CNT  256
#define D_IN   15
#define HDIM   128
#define BATCH  8192
#define NPAIR  256                  // 256 pairs of 16-row chunks per expert
#define BPE    4                    // blocks per expert -> grid 1024, 4 blocks/CU
#define NL2E   -1.44269504088896341f

typedef float f32x4 __attribute__((ext_vector_type(4)));
typedef short bf16x8 __attribute__((ext_vector_type(8)));
typedef unsigned int uint4v __attribute__((ext_vector_type(4)));

#define MFMA16(a, b, c) __builtin_amdgcn_mfma_f32_16x16x32_bf16((a), (b), (c), 0, 0, 0)
#define SCHED_FENCE() __builtin_amdgcn_sched_barrier(0)

// bf16 via round-half-up on the bit pattern (values finite here).
static __device__ inline unsigned short f2bf_rnd(float f) {
    unsigned u = __builtin_bit_cast(unsigned, f);
    return (unsigned short)((u + 0x8000u) >> 16);
}

// sigmoid with pre-scaled input az = -z*log2(e): s = rcp(1 + 2^az).
static __device__ inline float sg(float az) {
    float e = __builtin_amdgcn_exp2f(az);
    return __builtin_amdgcn_rcpf(1.0f + e);
}

// pack two sigmoid outputs ([0,1]) to a bf16 pair by TRUNCATION: 1 op.
// (<=1 ulp negative bias per element; random-sign w2 cancels it in the L2 sum.
//  NOT hand-written v_cvt_pk_bf16_f32: that asm corrupted results in R2/R14.)
static __device__ inline unsigned pack2t(float lo, float hi_) {
    unsigned a = __builtin_bit_cast(unsigned, lo);
    unsigned b = __builtin_bit_cast(unsigned, hi_);
#if __has_builtin(__builtin_amdgcn_perm)
    return __builtin_amdgcn_perm(b, a, 0x07060302u);   // D = {a.b2,a.b3,b.b2,b.b3}
#else
    return (a >> 16) | (b & 0xffff0000u);
#endif
}

// v_permlane32_swap_b32: a' = {a.g0,a.g1,b.g0,b.g1}, b' = {a.g2,a.g3,b.g2,b.g3}
static __device__ inline void pl32swap(unsigned &a, unsigned &b) {
#if __has_builtin(__builtin_amdgcn_permlane32_swap)
    auto r = __builtin_amdgcn_permlane32_swap(a, b, false, false);
    a = (unsigned)r[0];
    b = (unsigned)r[1];
#else
    asm volatile("v_permlane32_swap_b32 %0, %1" : "+v"(a), "+v"(b));
#endif
}

// v_permlane16_swap_b32: a' = {a.g0,b.g0,a.g2,b.g2}, b' = {a.g1,b.g1,a.g3,b.g3}
static __device__ inline void pl16swap(unsigned &a, unsigned &b) {
#if __has_builtin(__builtin_amdgcn_permlane16_swap)
    auto r = __builtin_amdgcn_permlane16_swap(a, b, false, false);
    a = (unsigned)r[0];
    b = (unsigned)r[1];
#else
    asm volatile("v_permlane16_swap_b32 %0, %1" : "+v"(a), "+v"(b));
#endif
}

static __device__ inline f32x4 zero4() { f32x4 z = {0.f, 0.f, 0.f, 0.f}; return z; }

// Redistribute two 16x16 C-tiles (pair-packed sigmoids) into one K=32 B-frag.
// (validated on-device R8-R19: absmax 0.0078)
static __device__ inline bf16x8 mk_bfrag(unsigned X0, unsigned X1, unsigned Y0, unsigned Y1) {
    pl32swap(X0, Y0);
    pl32swap(X1, Y1);
    pl16swap(X0, Y0);
    pl16swap(X1, Y1);
    uint4v u = {X0, X1, Y0, Y1};
    return __builtin_bit_cast(bf16x8, u);
}

// x[B][15] f32 -> xbf[B][16] bf16 with slot 15 = 1.0 (b1 partner)
__global__ __launch_bounds__(256)
void prep_x_kernel(const float* __restrict__ x, unsigned short* __restrict__ xbf)
{
    int i = blockIdx.x * 256 + threadIdx.x;
    if (i >= BATCH * 16) return;
    int row = i >> 4, k = i & 15;
    float v = (k < D_IN) ? x[row * D_IN + k] : 1.0f;
    xbf[i] = f2bf_rnd(v);
}

// FINAL (R18 config, session-best 142.3 us): 16x16x32 MFMA MLP, dual-chunk,
// fragment-ordered compressed LDS, (256,4) = 4 waves/SIMD no-spill.
// Key levers, each counter-verified this session:
//  - fragment-ordered LDS: lane i reads base + tile*1024 + i*16 (conflict-free;
//    bank conflicts 2.67e7 -> 1.5e6)
//  - compressed LDS (38.4KB) for 4 blocks/CU; known-zero lanes read a shared
//    zero line via quarter-uniform pointer select
//  - weights pre-scaled by -log2e: sigmoid = rcp(1+exp2(acc)), no multiply
//  - b2 bias as MFMA C-initializer (f32 LDS read, no bias MFMA)
//  - layer 3 as VALU dot + cross-q shuffle reduce (C/D map: lane(q,l15) reg r
//    = h2[ot*16+q*4+r][col l15]) — no L3 pack/redistribute/MFMA
//  - L1 pack by truncation (1 op); permlane16/32 swap redistribution
//  - dual-chunk shares every weight read; quad-chunk spills (R19) and more
//    waves are null (R16) — this is the measured optimum.
__global__ __launch_bounds__(256, 4)
void mlp256_kernel(const float* __restrict__ x, const unsigned short* __restrict__ xbf,
                   const float* __restrict__ W1, const float* __restrict__ b1,
                   const float* __restrict__ W2, const float* __restrict__ b2,
                   const float* __restrict__ W3, const float* __restrict__ b3,
                   float* __restrict__ dst, int use_xbf, int transposed)
{
    __shared__ __align__(16) unsigned short w2f[32 * 512];   // 32 KB
    __shared__ __align__(16) unsigned short w1f[8 * 256];    // 4 KB (lanes<32)
    __shared__ __align__(16) float          b2l[128];        // 512 B (f32, scaled)
    __shared__ __align__(16) float          w3l[128];        // 512 B (f32, natural order)
    __shared__ __align__(16) unsigned short zb[8];           // shared zero line

    const int tid  = threadIdx.x;
    const int wave = tid >> 6;
    const int lane = tid & 63;
    const int l15  = lane & 15;
    const int q    = lane >> 4;

    // grid = 1024: e = bid&255, rg = bid>>8 (0..3). Blocks e,e+256,e+512,e+768
    // share bid%8 -> same XCD under round-robin dispatch (W2 in one L2).
    const int bid = blockIdx.x;
    const int e   = bid & 255;
    const int rg  = bid >> 8;

    const float* w1p = W1 + e * (D_IN * HDIM);
    const float* b1p = b1 + e * HDIM;
    const float* w2p = W2 + e * (HDIM * HDIM);
    const float* b2p = b2 + e * HDIM;
    const float* w3p = W3 + e * HDIM;
    const float  b3v = b3[e];

    // ---- stage weights, fragment-ordered (prologue only) ----
    // W2: src (h,k) -> tile (h>>4)*4 + (k>>5), lane ((k>>3)&3)*16 + (h&15), j=k&7
    for (int i = tid; i < HDIM * HDIM; i += 256) {
        int h = i & 127, k = i >> 7;
        int t = ((h >> 4) << 2) + (k >> 5);
        int ln = (((k >> 3) & 3) << 4) + (h & 15);
        w2f[t * 512 + ln * 8 + (k & 7)] = f2bf_rnd(w2p[k * HDIM + h] * NL2E);
    }
    // W1 (+b1): 8 tiles x 32 lanes x 8; k = (ln>>4)*8 + j in 0..15
    for (int i = tid; i < 8 * 256; i += 256) {
        int t = i >> 8, ln = (i >> 3) & 31, j = i & 7;
        int k = (ln >> 4) * 8 + j, h = t * 16 + (ln & 15);
        float v = (k < D_IN) ? w1p[k * HDIM + h] : b1p[h];
        w1f[i] = f2bf_rnd(v * NL2E);
    }
    // b2 (scaled) as accumulator C-init; w3 f32 natural; zero line
    if (tid < 128) b2l[tid] = b2p[tid] * NL2E;
    if (tid < 128) w3l[tid] = w3p[tid];
    if (tid < 8)   zb[tid] = 0;

    __syncthreads();   // weights staged; waves independent from here

    // per-lane bases + selects (quarter-uniform; compile to v_cndmask on addr)
    const bool w1s = (lane < 32);
    const unsigned short* w1D = w1f + lane * 8;        // + t*256
    const unsigned short* w2B = w2f + lane * 8;        // + tile*512
    const float*          b2D = b2l + q * 4;           // + ot*16 (l15-independent)
    const float*          w3V = w3l + q * 4;           // + ot*16 (l15-independent)
    const int xoff = l15 * 16 + (q & 1) * 8;

    // pairs: slot = rg + 4*wave (0..15); p = slot + 16*j, 16 pairs per wave
    for (int p = rg + 4 * wave; p < NPAIR; p += 16) {
        const int cA = 2 * p, cB = 2 * p + 1;

        bf16x8 XA, XBv;
        if (use_xbf) {
            XA  = *reinterpret_cast<const bf16x8*>(xbf + (size_t)cA * 256 + xoff);
            XBv = *reinterpret_cast<const bf16x8*>(xbf + (size_t)cB * 256 + xoff);
        } else {
            const float* xa = x + (size_t)(cA * 16 + l15) * D_IN;
            const float* xb = x + (size_t)(cB * 16 + l15) * D_IN;
#pragma unroll
            for (int j = 0; j < 8; ++j) {
                int k = (q & 1) * 8 + j;
                XA[j]  = (short)f2bf_rnd((k < D_IN) ? xa[k] : 1.0f);
                XBv[j] = (short)f2bf_rnd((k < D_IN) ? xb[k] : 1.0f);
            }
        }

        // ---- layer 1, pairwise: two h-tiles -> one K=32 B-frag, both chunks ----
        bf16x8 H1A[4], H1B[4];
#pragma unroll
        for (int kb = 0; kb < 4; ++kb) {
            bf16x8 wa0 = *reinterpret_cast<const bf16x8*>(w1s ? (w1D + (2 * kb) * 256) : zb);
            f32x4 aa = MFMA16(wa0, XA,  zero4());
            f32x4 ba = MFMA16(wa0, XBv, zero4());
            bf16x8 wa1 = *reinterpret_cast<const bf16x8*>(w1s ? (w1D + (2 * kb + 1) * 256) : zb);
            f32x4 ab = MFMA16(wa1, XA,  zero4());
            f32x4 bb = MFMA16(wa1, XBv, zero4());
            H1A[kb] = mk_bfrag(pack2t(sg(aa[0]), sg(aa[1])), pack2t(sg(aa[2]), sg(aa[3])),
                               pack2t(sg(ab[0]), sg(ab[1])), pack2t(sg(ab[2]), sg(ab[3])));
            H1B[kb] = mk_bfrag(pack2t(sg(ba[0]), sg(ba[1])), pack2t(sg(ba[2]), sg(ba[3])),
                               pack2t(sg(bb[0]), sg(bb[1])), pack2t(sg(bb[2]), sg(bb[3])));
        }
        SCHED_FENCE();

        // ---- layer 2 (MFMA, b2 as C-init) + layer 3 (VALU dot) ----
        float oA = 0.0f, oB = 0.0f;
#pragma unroll
        for (int ot = 0; ot < 8; ++ot) {
            f32x4 binit = *reinterpret_cast<const f32x4*>(b2D + ot * 16);
            f32x4 cA2 = binit, cB2 = binit;
#pragma unroll
            for (int kb = 0; kb < 4; ++kb) {
                bf16x8 wa = *reinterpret_cast<const bf16x8*>(w2B + (ot * 4 + kb) * 512);
                cA2 = MFMA16(wa, H1A[kb], cA2);
                cB2 = MFMA16(wa, H1B[kb], cB2);
            }
            // lane (q,l15) reg r holds pre-act of h = ot*16 + q*4 + r, col l15
            f32x4 w3v = *reinterpret_cast<const f32x4*>(w3V + ot * 16);
#pragma unroll
            for (int r = 0; r < 4; ++r) {
                oA += sg(cA2[r]) * w3v[r];
                oB += sg(cB2[r]) * w3v[r];
            }
        }

        // cross-q reduce (cols split over 4 quarter-groups)
        oA += __shfl_xor(oA, 16);
        oA += __shfl_xor(oA, 32);
        oB += __shfl_xor(oB, 16);
        oB += __shfl_xor(oB, 32);

        if (q == 0) {   // col = l15
            float vA = oA + b3v;
            float vB = oB + b3v;
            const int bbA = cA * 16 + l15;
            const int bbB = cB * 16 + l15;
            if (transposed) {
                dst[(size_t)e * BATCH + bbA] = vA;
                dst[(size_t)e * BATCH + bbB] = vB;
            } else {
                dst[(size_t)bbA * E_CNT + e] = vA;
                dst[(size_t)bbB * E_CNT + e] = vB;
            }
        }
    }
}

// wsT[e][b] (256 x 8192) -> out[b][e] (8192 x 256), 64x64 LDS tiles
__global__ __launch_bounds__(256)
void transpose_out_kernel(const float* __restrict__ wsT, float* __restrict__ out)
{
    __shared__ float tile[64][65];
    const int tx = threadIdx.x & 63;
    const int ty = threadIdx.x >> 6;
    const int b0 = blockIdx.x * 64;
    const int e0 = blockIdx.y * 64;
#pragma unroll
    for (int r = ty; r < 64; r += 4)
        tile[r][tx] = wsT[(size_t)(e0 + r) * BATCH + b0 + tx];
    __syncthreads();
#pragma unroll
    for (int r = ty; r < 64; r += 4)
        out[(size_t)(b0 + r) * E_CNT + e0 + tx] = tile[tx][r];
}

extern "C" void kernel_launch(void* const* d_in, const int* in_sizes, int n_in,
                              void* d_out, int out_size, void* d_ws, size_t ws_size,
                              hipStream_t stream) {
    const float* x  = (const float*)d_in[0];
    const float* W1 = (const float*)d_in[1];
    const float* b1 = (const float*)d_in[2];
    const float* W2 = (const float*)d_in[3];
    const float* b2 = (const float*)d_in[4];
    const float* W3 = (const float*)d_in[5];
    const float* b3 = (const float*)d_in[6];
    float* out = (float*)d_out;

    const size_t XBF_BYTES = (size_t)BATCH * 16 * sizeof(unsigned short);  // 256 KB
    const size_t WST_BYTES = (size_t)E_CNT * BATCH * sizeof(float);        // 8 MB

    const bool have_xbf = ws_size >= XBF_BYTES + WST_BYTES;
    const bool have_wst = ws_size >= WST_BYTES;

    unsigned short* xbf = (unsigned short*)d_ws;
    float* wsT = have_xbf ? (float*)((char*)d_ws + XBF_BYTES) : (float*)d_ws;

    if (have_xbf)
        prep_x_kernel<<<dim3((BATCH * 16 + 255) / 256), dim3(256), 0, stream>>>(x, xbf);

    if (have_wst) {
        mlp256_kernel<<<dim3(E_CNT * BPE), dim3(256), 0, stream>>>(
            x, xbf, W1, b1, W2, b2, W3, b3, wsT, have_xbf ? 1 : 0, 1);
        transpose_out_kernel<<<dim3(BATCH / 64, E_CNT / 64), dim3(256), 0, stream>>>(
            wsT, out);
    } else {
        mlp256_kernel<<<dim3(E_CNT * BPE), dim3(256), 0, stream>>>(
            x, xbf, W1, b1, W2, b2, W3, b3, out, 0, 0);
    }
}